// Round 2
// baseline (527.506 us; speedup 1.0000x reference)
//
#include <hip/hip_runtime.h>
#include <cmath>

// ---------------------------------------------------------------------------
// Fused 3D SSIM, separable Gaussian 11-tap, VALID. fp32 (2,1,192,192,192).
// One block = one 12^3 output tile; all conv work in LDS; no global scratch
// beyond 16 bytes (sum + minmax).
// ---------------------------------------------------------------------------

#define WSZ 11
#define DIN 192
#define DOUTS 182
#define TO 12              // output tile edge
#define II 22              // input tile edge (TO + WSZ - 1)
#define NT 16              // tiles per axis: 16*12 = 192 >= 182
static constexpr double SOUT = 2.0 * 182.0 * 182.0 * 182.0;  // 12,057,136

struct G11 { float g[WSZ]; };

__device__ __forceinline__ unsigned int enc_f(float f) {
    unsigned int u = __float_as_uint(f);
    return (u & 0x80000000u) ? ~u : (u | 0x80000000u);
}
__device__ __forceinline__ float dec_f(unsigned int u) {
    return (u & 0x80000000u) ? __uint_as_float(u & 0x7FFFFFFFu) : __uint_as_float(~u);
}

// ---------------------------------------------------------------------------
__global__ void k_init(unsigned int* mm, double* sum) {
    sum[0] = 0.0;
    mm[0] = 0u;           // encoded -inf (max accumulator)
    mm[1] = 0xFFFFFFFFu;  // encoded +inf (min accumulator)
}

// ---------------------------------------------------------------------------
__global__ __launch_bounds__(256) void k_minmax(const float4* __restrict__ img1,
                                                int n4, unsigned int* mm) {
    float mx = -1e30f, mn = 1e30f;
    for (int i = blockIdx.x * blockDim.x + threadIdx.x; i < n4;
         i += gridDim.x * blockDim.x) {
        float4 v = img1[i];
        mx = fmaxf(mx, fmaxf(fmaxf(v.x, v.y), fmaxf(v.z, v.w)));
        mn = fminf(mn, fminf(fminf(v.x, v.y), fminf(v.z, v.w)));
    }
    #pragma unroll
    for (int o = 32; o; o >>= 1) {
        mx = fmaxf(mx, __shfl_down(mx, o));
        mn = fminf(mn, __shfl_down(mn, o));
    }
    __shared__ float smx[4], smn[4];
    int lane = threadIdx.x & 63, wv = threadIdx.x >> 6;
    if (lane == 0) { smx[wv] = mx; smn[wv] = mn; }
    __syncthreads();
    if (threadIdx.x == 0) {
        #pragma unroll
        for (int i = 1; i < 4; i++) { mx = fmaxf(mx, smx[i]); mn = fminf(mn, smn[i]); }
        atomicMax(&mm[0], enc_f(mx));
        atomicMin(&mm[1], enc_f(mn));
    }
}

// ---------------------------------------------------------------------------
// Load one 22-float W-row from global, zero-filling chunks past the array
// edge (those taps only feed discarded outputs). w0 is a multiple of 12 ->
// base is 16B aligned; chunks are float4-aligned.
__device__ __forceinline__ void load_row(const float* __restrict__ img,
                                         int n, int dr, int hr, int w0,
                                         float v[II]) {
    const float* p = img + ((n * DIN + dr) * DIN + hr) * DIN + w0;
    #pragma unroll
    for (int c = 0; c < 5; c++) {
        if (w0 + c * 4 + 3 < DIN) {   // wave-uniform (w0 uniform per block)
            float4 f = *reinterpret_cast<const float4*>(p + c * 4);
            v[c*4+0] = f.x; v[c*4+1] = f.y; v[c*4+2] = f.z; v[c*4+3] = f.w;
        } else {
            v[c*4+0] = v[c*4+1] = v[c*4+2] = v[c*4+3] = 0.f;
        }
    }
    if (w0 + 21 < DIN) { v[20] = p[20]; v[21] = p[21]; }
    else               { v[20] = 0.f;   v[21] = 0.f;   }
}

// W-conv of src row and src^2 row -> t1a, t1b.  t1 layout [x][z][y22].
__device__ __forceinline__ void conv_w_sq(const float* __restrict__ img,
                                          int n, int d0, int h0, int w0,
                                          float* t1a, float* t1b,
                                          const G11& gw, int tid) {
    for (int u = tid; u < II * II; u += 256) {
        int z = u / II, y = u - z * II;
        int dr = min(d0 + z, DIN - 1);
        int hr = min(h0 + y, DIN - 1);
        float v[II];
        load_row(img, n, dr, hr, w0, v);
        float s[II];
        #pragma unroll
        for (int j = 0; j < II; j++) s[j] = v[j] * v[j];
        #pragma unroll
        for (int x = 0; x < TO; x++) {
            float a0 = 0.f, a1 = 0.f;
            #pragma unroll
            for (int k = 0; k < WSZ; k++) {
                a0 = fmaf(gw.g[k], v[x + k], a0);
                a1 = fmaf(gw.g[k], s[x + k], a1);
            }
            t1a[(x * II + z) * II + y] = a0;
            t1b[(x * II + z) * II + y] = a1;
        }
    }
}

// W-conv of img1*img2 -> t1a.
__device__ __forceinline__ void conv_w_prod(const float* __restrict__ i1,
                                            const float* __restrict__ i2,
                                            int n, int d0, int h0, int w0,
                                            float* t1a, const G11& gw, int tid) {
    for (int u = tid; u < II * II; u += 256) {
        int z = u / II, y = u - z * II;
        int dr = min(d0 + z, DIN - 1);
        int hr = min(h0 + y, DIN - 1);
        float v1[II], v2[II];
        load_row(i1, n, dr, hr, w0, v1);
        load_row(i2, n, dr, hr, w0, v2);
        float p[II];
        #pragma unroll
        for (int j = 0; j < II; j++) p[j] = v1[j] * v2[j];
        #pragma unroll
        for (int x = 0; x < TO; x++) {
            float a = 0.f;
            #pragma unroll
            for (int k = 0; k < WSZ; k++) a = fmaf(gw.g[k], p[x + k], a);
            t1a[(x * II + z) * II + y] = a;
        }
    }
}

// H-conv: t1 [x][z][y22] -> t2 [y][x][z22]. Contiguous float2 reads.
__device__ __forceinline__ void conv_h(const float* t1, float* t2,
                                       const G11& gw, int tid) {
    for (int u = tid; u < TO * II; u += 256) {   // u = x*22 + z
        float v[II];
        #pragma unroll
        for (int j = 0; j < 11; j++) {
            float2 f = reinterpret_cast<const float2*>(t1 + u * II)[j];
            v[2*j] = f.x; v[2*j+1] = f.y;
        }
        int x = u / II, z = u - (u / II) * II;
        #pragma unroll
        for (int oy = 0; oy < TO; oy++) {
            float a = 0.f;
            #pragma unroll
            for (int k = 0; k < WSZ; k++) a = fmaf(gw.g[k], v[oy + k], a);
            t2[(oy * TO + x) * II + z] = a;
        }
    }
}

// D-conv: t2 [y][x][z22] -> 12 outputs in registers (threads tid<144).
__device__ __forceinline__ void conv_d(const float* t2, float* dst,
                                       const G11& gw, int tid) {
    if (tid < TO * TO) {
        float v[II];
        #pragma unroll
        for (int j = 0; j < 11; j++) {
            float2 f = reinterpret_cast<const float2*>(t2 + tid * II)[j];
            v[2*j] = f.x; v[2*j+1] = f.y;
        }
        #pragma unroll
        for (int zz = 0; zz < TO; zz++) {
            float a = 0.f;
            #pragma unroll
            for (int k = 0; k < WSZ; k++) a = fmaf(gw.g[k], v[zz + k], a);
            dst[zz] = a;
        }
    }
}

// ---------------------------------------------------------------------------
__global__ __launch_bounds__(256, 2) void k_ssim(const float* __restrict__ img1,
                                                 const float* __restrict__ img2,
                                                 const unsigned int* __restrict__ mm,
                                                 double* __restrict__ sum, G11 gw) {
    __shared__ float t1a[II * TO * II];  // 5808 floats
    __shared__ float t1b[II * TO * II];  // 5808 floats
    __shared__ float t2 [TO * TO * II];  // 3168 floats
    __shared__ float sred[4];

    int b  = blockIdx.x;
    int tw = b & 15, th = (b >> 4) & 15, td = (b >> 8) & 15, n = b >> 12;
    int w0 = tw * TO, h0 = th * TO, d0 = td * TO;
    int tid = threadIdx.x;

    float r[5][TO];  // D-conv results: mu1, mu2, E[x1^2], E[x2^2], E[x1x2]

    // --- channel group A: x1, x1^2 ---
    conv_w_sq(img1, n, d0, h0, w0, t1a, t1b, gw, tid);
    __syncthreads();
    conv_h(t1a, t2, gw, tid);
    __syncthreads();
    conv_d(t2, r[0], gw, tid);
    __syncthreads();
    conv_h(t1b, t2, gw, tid);
    __syncthreads();
    conv_d(t2, r[2], gw, tid);
    __syncthreads();

    // --- channel group B: x2, x2^2 ---
    conv_w_sq(img2, n, d0, h0, w0, t1a, t1b, gw, tid);
    __syncthreads();
    conv_h(t1a, t2, gw, tid);
    __syncthreads();
    conv_d(t2, r[1], gw, tid);
    __syncthreads();
    conv_h(t1b, t2, gw, tid);
    __syncthreads();
    conv_d(t2, r[3], gw, tid);
    __syncthreads();

    // --- channel group C: x1*x2 ---
    conv_w_prod(img1, img2, n, d0, h0, w0, t1a, gw, tid);
    __syncthreads();
    conv_h(t1a, t2, gw, tid);
    __syncthreads();
    conv_d(t2, r[4], gw, tid);

    // --- SSIM + reduction ---
    float maxv = dec_f(mm[0]);
    float minv = dec_f(mm[1]);
    float max_val = (maxv > 128.0f) ? 255.0f : 1.0f;
    float min_val = (minv < -0.5f) ? -1.0f : 0.0f;
    float L  = max_val - min_val;
    float C1 = 0.01f * L; C1 *= C1;
    float C2 = 0.03f * L; C2 *= C2;

    float local = 0.f;
    if (tid < TO * TO) {
        int y = tid / TO, x = tid - (tid / TO) * TO;
        int oh = h0 + y, ow = w0 + x;
        if (oh < DOUTS && ow < DOUTS) {
            #pragma unroll
            for (int zz = 0; zz < TO; zz++) {
                int od = d0 + zz;
                if (od < DOUTS) {
                    float mu1 = r[0][zz], mu2 = r[1][zz];
                    float mu1s = mu1 * mu1, mu2s = mu2 * mu2, mu12 = mu1 * mu2;
                    float s1  = r[2][zz] - mu1s;
                    float s2  = r[3][zz] - mu2s;
                    float s12 = r[4][zz] - mu12;
                    float v1  = 2.0f * s12 + C2;
                    float v2  = s1 + s2 + C2;
                    float num = (2.0f * mu12 + C1) * v1;
                    float den = (mu1s + mu2s + C1) * v2;
                    local += num / den;
                }
            }
        }
    }
    #pragma unroll
    for (int o = 32; o; o >>= 1) local += __shfl_down(local, o);
    if ((tid & 63) == 0) sred[tid >> 6] = local;
    __syncthreads();
    if (tid == 0)
        atomicAdd(sum, (double)(sred[0] + sred[1] + sred[2] + sred[3]));
}

// ---------------------------------------------------------------------------
__global__ void k_final(const double* __restrict__ sum, float* __restrict__ out) {
    out[0] = (float)(sum[0] / SOUT);
}

// ---------------------------------------------------------------------------
extern "C" void kernel_launch(void* const* d_in, const int* in_sizes, int n_in,
                              void* d_out, int out_size, void* d_ws, size_t ws_size,
                              hipStream_t stream) {
    const float* img1 = (const float*)d_in[0];
    const float* img2 = (const float*)d_in[1];
    float* out = (float*)d_out;

    char* ws = (char*)d_ws;
    double*       sum = (double*)ws;              // 8 B
    unsigned int* mm  = (unsigned int*)(ws + 8);  // 8 B

    // Gaussian weights: f64 compute, normalize, cast to f32 (matches ref).
    G11 g;
    {
        double gd[WSZ], s = 0.0;
        for (int i = 0; i < WSZ; i++) {
            double d = (double)(i - WSZ / 2);
            gd[i] = std::exp(-(d * d) / (2.0 * 1.5 * 1.5));
            s += gd[i];
        }
        for (int i = 0; i < WSZ; i++) g.g[i] = (float)(gd[i] / s);
    }

    int n_img = 2 * DIN * DIN * DIN;  // 14,155,776

    k_init<<<1, 1, 0, stream>>>(mm, sum);
    k_minmax<<<1024, 256, 0, stream>>>((const float4*)img1, n_img / 4, mm);
    k_ssim<<<2 * NT * NT * NT, 256, 0, stream>>>(img1, img2, mm, sum, g);
    k_final<<<1, 1, 0, stream>>>(sum, out);
}